// Round 2
// baseline (1172.019 us; speedup 1.0000x reference)
//
#include <hip/hip_runtime.h>
#include <hip/hip_bf16.h>

#define EPSV 1e-5f

// ---------- float<->orderable uint encoding for atomic max ----------
__device__ __forceinline__ unsigned enc_f(float f){
  unsigned u = __float_as_uint(f);
  return (u & 0x80000000u) ? ~u : (u | 0x80000000u);
}
__device__ __forceinline__ float dec_f(unsigned k){
  unsigned u = (k & 0x80000000u) ? (k & 0x7fffffffu) : ~k;
  return __uint_as_float(u);
}

// ---------------- degree histogram ----------------
__global__ void hist_kernel(const int* __restrict__ dst, int* __restrict__ deg, int E){
  int i = blockIdx.x*256 + threadIdx.x;
  if (i < E) atomicAdd(&deg[dst[i]], 1);
}

// ---------------- scan (exclusive, over N degree counts) ----------------
__global__ void scan_partial(const int* __restrict__ deg, int* __restrict__ bsums, int N){
  __shared__ int sd[256];
  int t = threadIdx.x;
  int base = blockIdx.x*1024 + t*4;
  int s = 0;
  if (base+0 < N) s += deg[base+0];
  if (base+1 < N) s += deg[base+1];
  if (base+2 < N) s += deg[base+2];
  if (base+3 < N) s += deg[base+3];
  sd[t]=s; __syncthreads();
  for (int off=128; off>0; off>>=1){
    if (t<off) sd[t]+=sd[t+off];
    __syncthreads();
  }
  if (t==0) bsums[blockIdx.x]=sd[0];
}

__global__ void scan_bsums(int* bsums, int* row_start, int B, int N, int E){
  if (threadIdx.x==0 && blockIdx.x==0){
    int run=0;
    for (int b=0;b<B;b++){ int v=bsums[b]; bsums[b]=run; run+=v; }
    row_start[N]=E;
  }
}

__global__ void scan_final(const int* __restrict__ deg, const int* __restrict__ bsums,
                           int* __restrict__ row_start, int* __restrict__ cursor, int N){
  __shared__ int sd[256];
  int t=threadIdx.x, b=blockIdx.x;
  int base=b*1024+t*4;
  int v0=0,v1=0,v2=0,v3=0;
  if (base+0<N) v0=deg[base+0];
  if (base+1<N) v1=deg[base+1];
  if (base+2<N) v2=deg[base+2];
  if (base+3<N) v3=deg[base+3];
  int s=v0+v1+v2+v3;
  sd[t]=s; __syncthreads();
  for (int off=1; off<256; off<<=1){
    int x = (t>=off)?sd[t-off]:0;
    __syncthreads();
    sd[t]+=x;
    __syncthreads();
  }
  int excl = sd[t]-s + bsums[b];
  int e0=excl, e1=excl+v0, e2=e1+v1, e3=e2+v2;
  if (base+0<N){ row_start[base+0]=e0; cursor[base+0]=e0; }
  if (base+1<N){ row_start[base+1]=e1; cursor[base+1]=e1; }
  if (base+2<N){ row_start[base+2]=e2; cursor[base+2]=e2; }
  if (base+3<N){ row_start[base+3]=e3; cursor[base+3]=e3; }
}

__global__ void dinv_kernel(const int* __restrict__ deg, float* __restrict__ dinv, int N){
  int i = blockIdx.x*256 + threadIdx.x;
  if (i < N) dinv[i] = rsqrtf((float)deg[i] + 1.0f);
}

__global__ void scatter_kernel(const int* __restrict__ src, const int* __restrict__ dst,
                               int* __restrict__ cursor, int* __restrict__ csr_src, int E){
  int i = blockIdx.x*256 + threadIdx.x;
  if (i < E){
    int d = dst[i];
    int pos = atomicAdd(&cursor[d], 1);
    csr_src[pos] = src[i];
  }
}

// ================= GEMM macros =================
// Per-k FMA: 8 rows x 4 cols, named float4 accumulators.
#define ROWFMA(ACC, XV) \
  ACC.x = __builtin_fmaf((XV), w.x, ACC.x); \
  ACC.y = __builtin_fmaf((XV), w.y, ACC.y); \
  ACC.z = __builtin_fmaf((XV), w.z, ACC.z); \
  ACC.w = __builtin_fmaf((XV), w.w, ACC.w);

#define FMA_STEP(K) { \
  const float4 w   = *(const float4*)(Wl + (K)*128 + wb); \
  const float4 xlo = *(const float4*)(Xl + (K)*64 + r0); \
  const float4 xhi = *(const float4*)(Xl + (K)*64 + r0 + 4); \
  ROWFMA(acc0, xlo.x) ROWFMA(acc1, xlo.y) ROWFMA(acc2, xlo.z) ROWFMA(acc3, xlo.w) \
  ROWFMA(acc4, xhi.x) ROWFMA(acc5, xhi.y) ROWFMA(acc6, xhi.z) ROWFMA(acc7, xhi.w) }

// Stage W chunk [L x 128] and X chunk transposed Xl[k][row], then accumulate.
// xa: [N x Da], xb: [N x Db] (concat), W: [(Da+Db) x 128].
#define GEMM_LOOP \
  const int tid  = threadIdx.x; \
  const int lane = tid & 63; \
  const int wave = tid >> 6; \
  const int half = lane >> 5; \
  const int ff   = lane & 31; \
  const int r0   = wave*16 + half*8; \
  const int wb   = ff << 2; \
  const int srow = tid >> 2; \
  const int skg  = (tid & 3) << 4; \
  const int R_s  = rowBase + srow; \
  float4 acc0={0,0,0,0},acc1={0,0,0,0},acc2={0,0,0,0},acc3={0,0,0,0}; \
  float4 acc4={0,0,0,0},acc5={0,0,0,0},acc6={0,0,0,0},acc7={0,0,0,0}; \
  for (int kc = 0; kc < D; kc += 64){ \
    const int L = (D - kc < 64) ? (D - kc) : 64; \
    __syncthreads(); \
    { \
      const int nf4 = (L*128) >> 2; \
      const float4* Wg = (const float4*)(W + (size_t)kc*128); \
      float4* Wl4 = (float4*)Wl; \
      for (int idx = tid; idx < nf4; idx += 256) Wl4[idx] = Wg[idx]; \
    } \
    if (L == 64 && kc + 64 <= Da){ \
      float4 v0={0,0,0,0},v1={0,0,0,0},v2={0,0,0,0},v3={0,0,0,0}; \
      if (R_s < N){ \
        const float4* xr = (const float4*)(xa + (size_t)R_s*Da + kc + skg); \
        v0 = xr[0]; v1 = xr[1]; v2 = xr[2]; v3 = xr[3]; \
      } \
      Xl[(skg+ 0)*64 + srow]=v0.x; Xl[(skg+ 1)*64 + srow]=v0.y; \
      Xl[(skg+ 2)*64 + srow]=v0.z; Xl[(skg+ 3)*64 + srow]=v0.w; \
      Xl[(skg+ 4)*64 + srow]=v1.x; Xl[(skg+ 5)*64 + srow]=v1.y; \
      Xl[(skg+ 6)*64 + srow]=v1.z; Xl[(skg+ 7)*64 + srow]=v1.w; \
      Xl[(skg+ 8)*64 + srow]=v2.x; Xl[(skg+ 9)*64 + srow]=v2.y; \
      Xl[(skg+10)*64 + srow]=v2.z; Xl[(skg+11)*64 + srow]=v2.w; \
      Xl[(skg+12)*64 + srow]=v3.x; Xl[(skg+13)*64 + srow]=v3.y; \
      Xl[(skg+14)*64 + srow]=v3.z; Xl[(skg+15)*64 + srow]=v3.w; \
    } else if (skg < L){ \
      const int lim = (L - skg < 16) ? (L - skg) : 16; \
      for (int i2=0;i2<lim;i2++){ \
        const int gk = kc + skg + i2; \
        float v = 0.f; \
        if (R_s < N) v = (gk < Da) ? xa[(size_t)R_s*Da + gk] \
                                   : xb[(size_t)R_s*Db + (gk - Da)]; \
        Xl[(skg+i2)*64 + srow] = v; \
      } \
    } \
    __syncthreads(); \
    if (L == 64){ \
      _Pragma("unroll 4") \
      for (int k=0;k<64;k++){ FMA_STEP(k) } \
    } else { \
      for (int k=0;k<L;k++){ FMA_STEP(k) } \
    } \
  }

__global__ __launch_bounds__(256) void gemm_kernel(
    const float* __restrict__ xa, const float* __restrict__ xb,
    const float* __restrict__ W, float* __restrict__ out,
    int N, int D, int Da, int Db)
{
  __shared__ float Wl[64*128];
  __shared__ float Xl[64*64];
  const int rowBase = blockIdx.x*64;
  GEMM_LOOP
  const int R0 = rowBase + r0;
#define STORE_ROW(ACC, RR) { \
    int R = R0 + (RR); \
    if (R < N){ *(float4*)(out + (size_t)R*128 + wb) = ACC; } }
  STORE_ROW(acc0,0) STORE_ROW(acc1,1) STORE_ROW(acc2,2) STORE_ROW(acc3,3)
  STORE_ROW(acc4,4) STORE_ROW(acc5,5) STORE_ROW(acc6,6) STORE_ROW(acc7,7)
#undef STORE_ROW
}

// attention gate: gate[i] = tanh(x[i]@W + b1) . w2 + b2
__global__ __launch_bounds__(256) void att_kernel(
    const float* __restrict__ xa, const float* __restrict__ W,
    const float* __restrict__ b1, const float* __restrict__ w2,
    const float* __restrict__ b2, float* __restrict__ gate, int N)
{
  __shared__ float Wl[64*128];
  __shared__ float Xl[64*64];
  const int rowBase = blockIdx.x*64;
  const float* xb = xa;  // unused (Db=0)
  const int D = 128, Da = 128, Db = 0;
  GEMM_LOOP
  const int R0 = rowBase + r0;
  const float4 b1v = *(const float4*)(b1 + (ff<<2));
  const float4 w2v = *(const float4*)(w2 + (ff<<2));
  const float bias2 = b2[0];
#define ATT_ROW(ACC, RR) { \
    float p = tanhf(ACC.x + b1v.x)*w2v.x + tanhf(ACC.y + b1v.y)*w2v.y \
            + tanhf(ACC.z + b1v.z)*w2v.z + tanhf(ACC.w + b1v.w)*w2v.w; \
    p += __shfl_xor(p, 1);  p += __shfl_xor(p, 2); \
    p += __shfl_xor(p, 4);  p += __shfl_xor(p, 8); \
    p += __shfl_xor(p, 16); \
    if (ff == 0){ int R = R0 + (RR); if (R < N) gate[R] = p + bias2; } }
  ATT_ROW(acc0,0) ATT_ROW(acc1,1) ATT_ROW(acc2,2) ATT_ROW(acc3,3)
  ATT_ROW(acc4,4) ATT_ROW(acc5,5) ATT_ROW(acc6,6) ATT_ROW(acc7,7)
#undef ATT_ROW
}

// ---------------- gather: one wave per node, float2 per lane (128 feats) ----------------
// mode 0: out = relu(bn(agg + bias));  mode 2: out = x1in + x2in + relu(bn(agg + bias))
__global__ void gather_kernel(
    const float* __restrict__ h, const float* __restrict__ dinv,
    const int* __restrict__ row_start, const int* __restrict__ csr_src,
    const float* __restrict__ bias, const float* __restrict__ bng, const float* __restrict__ bnb,
    const float* __restrict__ x1in, const float* __restrict__ x2in,
    float* __restrict__ out, int N, int mode)
{
  int gwid = (blockIdx.x * blockDim.x + threadIdx.x) >> 6;
  int lane = threadIdx.x & 63;
  if (gwid >= N) return;
  const int i = gwid;
  const float di = dinv[i];
  const float2* h2 = (const float2*)h;
  float2 hv = h2[(size_t)i*64 + lane];
  float w0 = di*di;
  float ax = hv.x*w0, ay = hv.y*w0;
  const int s0 = row_start[i], s1 = row_start[i+1];
  for (int base = s0; base < s1; base += 64){
    const int nloc = (s1 - base < 64) ? (s1 - base) : 64;
    int sv = 0; float nv = 0.f;
    if (lane < nloc){ sv = csr_src[base + lane]; nv = dinv[sv]*di; }
    for (int j=0;j<nloc;j++){
      int   sj = __shfl(sv, j);
      float nj = __shfl(nv, j);
      float2 hh = h2[(size_t)sj*64 + lane];
      ax = __builtin_fmaf(hh.x, nj, ax);
      ay = __builtin_fmaf(hh.y, nj, ay);
    }
  }
  const int f0 = lane*2;
  const float bsc = rsqrtf(1.0f + EPSV);
  float sA = bng[f0]*bsc,   sB = bng[f0+1]*bsc;
  float vA = fmaxf(0.f, (ax + bias[f0  ])*sA + bnb[f0  ]);
  float vB = fmaxf(0.f, (ay + bias[f0+1])*sB + bnb[f0+1]);
  if (mode == 2){
    vA += x1in[(size_t)i*128 + f0  ] + x2in[(size_t)i*128 + f0  ];
    vB += x1in[(size_t)i*128 + f0+1] + x2in[(size_t)i*128 + f0+1];
  }
  float2 o; o.x=vA; o.y=vB;
  ((float2*)out)[(size_t)i*64 + lane] = o;
}

// ---------------- segment softmax pieces ----------------
__global__ void segmax_kernel(const float* __restrict__ gate, const int* __restrict__ batch,
                              unsigned* __restrict__ mg, int N){
  __shared__ unsigned sm[8];
  int t = threadIdx.x;
  if (t < 8) sm[t] = 0u;
  __syncthreads();
  int i = blockIdx.x*256 + t;
  if (i < N) atomicMax(&sm[batch[i]], enc_f(gate[i]));
  __syncthreads();
  if (t < 8) atomicMax(&mg[t], sm[t]);
}

__global__ void expsum_kernel(const float* __restrict__ gate, const int* __restrict__ batch,
                              const unsigned* __restrict__ mg, float* __restrict__ aex,
                              float* __restrict__ denom, int N){
  __shared__ float sd[8];
  int t = threadIdx.x;
  if (t < 8) sd[t] = 0.f;
  __syncthreads();
  int i = blockIdx.x*256 + t;
  if (i < N){
    int g = batch[i];
    float m = dec_f(mg[g]);
    float av = expf(gate[i] - m);
    aex[i] = av;
    atomicAdd(&sd[g], av);
  }
  __syncthreads();
  if (t < 8) atomicAdd(&denom[t], sd[t]);
}

__global__ void pooled_kernel(const float* __restrict__ aex, const float* __restrict__ xo,
                              const int* __restrict__ batch, float* __restrict__ pooled, int N){
  int t = threadIdx.x;
  int hlf = t >> 7;
  int f = t & 127;
  int nb = gridDim.x;
  int per = (N + nb - 1)/nb;
  int start = blockIdx.x*per;
  int end = (N < start + per) ? N : (start + per);
  float acc = 0.f; int gcur = -1;
  for (int i = start + hlf; i < end; i += 2){
    int g = batch[i];
    if (g != gcur){
      if (gcur >= 0) atomicAdd(&pooled[gcur*128 + f], acc);
      acc = 0.f; gcur = g;
    }
    acc = __builtin_fmaf(aex[i], xo[(size_t)i*128 + f], acc);
  }
  if (gcur >= 0) atomicAdd(&pooled[gcur*128 + f], acc);
}

// ---------------- classifier head (single block) ----------------
__global__ __launch_bounds__(256) void classifier_kernel(
    const float* __restrict__ pooled, const float* __restrict__ denom,
    const float* __restrict__ w1, const float* __restrict__ b1,
    const float* __restrict__ g1, const float* __restrict__ be1,
    const float* __restrict__ w2, const float* __restrict__ b2,
    const float* __restrict__ g2, const float* __restrict__ be2,
    const float* __restrict__ w3, const float* __restrict__ b3,
    float* __restrict__ outp)
{
  __shared__ float pl[8*128];
  __shared__ float h1[8*256];
  __shared__ float h2l[8*128];
  int t = threadIdx.x;
  for (int idx = t; idx < 1024; idx += 256){
    int g = idx >> 7;
    pl[idx] = pooled[idx] / denom[g];
  }
  __syncthreads();
  {
    float a0=0,a1=0,a2=0,a3=0,a4=0,a5=0,a6=0,a7=0;
    for (int k=0; k<128; k++){
      float w = w1[k*256 + t];
      a0 = __builtin_fmaf(pl[0*128+k], w, a0);
      a1 = __builtin_fmaf(pl[1*128+k], w, a1);
      a2 = __builtin_fmaf(pl[2*128+k], w, a2);
      a3 = __builtin_fmaf(pl[3*128+k], w, a3);
      a4 = __builtin_fmaf(pl[4*128+k], w, a4);
      a5 = __builtin_fmaf(pl[5*128+k], w, a5);
      a6 = __builtin_fmaf(pl[6*128+k], w, a6);
      a7 = __builtin_fmaf(pl[7*128+k], w, a7);
    }
    float s = g1[t]*rsqrtf(1.0f + EPSV);
    float bb = b1[t], tb = be1[t];
    h1[0*256+t] = fmaxf(0.f, (a0+bb)*s + tb);
    h1[1*256+t] = fmaxf(0.f, (a1+bb)*s + tb);
    h1[2*256+t] = fmaxf(0.f, (a2+bb)*s + tb);
    h1[3*256+t] = fmaxf(0.f, (a3+bb)*s + tb);
    h1[4*256+t] = fmaxf(0.f, (a4+bb)*s + tb);
    h1[5*256+t] = fmaxf(0.f, (a5+bb)*s + tb);
    h1[6*256+t] = fmaxf(0.f, (a6+bb)*s + tb);
    h1[7*256+t] = fmaxf(0.f, (a7+bb)*s + tb);
  }
  __syncthreads();
  if (t < 128){
    float a0=0,a1=0,a2=0,a3=0,a4=0,a5=0,a6=0,a7=0;
    for (int k=0; k<256; k++){
      float w = w2[k*128 + t];
      a0 = __builtin_fmaf(h1[0*256+k], w, a0);
      a1 = __builtin_fmaf(h1[1*256+k], w, a1);
      a2 = __builtin_fmaf(h1[2*256+k], w, a2);
      a3 = __builtin_fmaf(h1[3*256+k], w, a3);
      a4 = __builtin_fmaf(h1[4*256+k], w, a4);
      a5 = __builtin_fmaf(h1[5*256+k], w, a5);
      a6 = __builtin_fmaf(h1[6*256+k], w, a6);
      a7 = __builtin_fmaf(h1[7*256+k], w, a7);
    }
    float s = g2[t]*rsqrtf(1.0f + EPSV);
    float bb = b2[t], tb = be2[t];
    h2l[0*128+t] = fmaxf(0.f, (a0+bb)*s + tb);
    h2l[1*128+t] = fmaxf(0.f, (a1+bb)*s + tb);
    h2l[2*128+t] = fmaxf(0.f, (a2+bb)*s + tb);
    h2l[3*128+t] = fmaxf(0.f, (a3+bb)*s + tb);
    h2l[4*128+t] = fmaxf(0.f, (a4+bb)*s + tb);
    h2l[5*128+t] = fmaxf(0.f, (a5+bb)*s + tb);
    h2l[6*128+t] = fmaxf(0.f, (a6+bb)*s + tb);
    h2l[7*128+t] = fmaxf(0.f, (a7+bb)*s + tb);
  }
  __syncthreads();
  if (t < 40){
    int g = t/5, c = t%5;
    float s = 0.f;
    for (int k=0; k<128; k++) s = __builtin_fmaf(h2l[g*128+k], w3[k*5+c], s);
    outp[t] = s + b3[c];
  }
}

extern "C" void kernel_launch(void* const* d_in, const int* in_sizes, int n_in,
                              void* d_out, int out_size, void* d_ws, size_t ws_size,
                              hipStream_t stream)
{
  const float* cnn   = (const float*)d_in[0];
  const float* morph = (const float*)d_in[1];
  const int*   eidx  = (const int*)d_in[2];
  const int*   batch = (const int*)d_in[3];
  const float* g1w = (const float*)d_in[4];
  const float* g1b = (const float*)d_in[5];
  const float* g2w = (const float*)d_in[6];
  const float* g2b = (const float*)d_in[7];
  const float* g3w = (const float*)d_in[8];
  const float* g3b = (const float*)d_in[9];
  const float* bn1g=(const float*)d_in[10], *bn1b=(const float*)d_in[11];
  const float* bn2g=(const float*)d_in[12], *bn2b=(const float*)d_in[13];
  const float* bn3g=(const float*)d_in[14], *bn3b=(const float*)d_in[15];
  const float* aw1=(const float*)d_in[16], *ab1=(const float*)d_in[17];
  const float* aw2=(const float*)d_in[18], *ab2=(const float*)d_in[19];
  const float* cw1=(const float*)d_in[20], *cb1=(const float*)d_in[21];
  const float* c1g=(const float*)d_in[22], *c1b=(const float*)d_in[23];
  const float* cw2=(const float*)d_in[24], *cb2=(const float*)d_in[25];
  const float* c2g=(const float*)d_in[26], *c2b=(const float*)d_in[27];
  const float* cw3=(const float*)d_in[28], *cb3=(const float*)d_in[29];

  const int N = in_sizes[3];
  const int E = in_sizes[2] / 2;
  const int CNNW = in_sizes[0] / N;   // 768
  const int MOR  = in_sizes[1] / N;   // 6
  const int D = CNNW + MOR;           // 774

  char* p = (char*)d_ws;
  auto alloc = [&](size_t bytes)->char* {
    char* r = p; p += (bytes + 255) & ~(size_t)255; return r;
  };
  float* hbuf  = (float*)alloc((size_t)N*128*4);
  float* x1    = (float*)alloc((size_t)N*128*4);
  float* x2    = (float*)alloc((size_t)N*128*4);
  float* dinv  = (float*)alloc((size_t)N*4);
  float* gate  = (float*)alloc((size_t)N*4);
  float* aex   = (float*)alloc((size_t)N*4);
  char* zstart = p;
  int* deg      = (int*)alloc((size_t)N*4);
  unsigned* mg  = (unsigned*)alloc(8*4);
  float* denom  = (float*)alloc(8*4);
  float* pooled = (float*)alloc(8*128*4);
  size_t zbytes = (size_t)(p - zstart);
  int* row_start=(int*)alloc((size_t)(N+1)*4);
  int* cursor  = (int*)alloc((size_t)N*4);
  int* csr_src = (int*)alloc((size_t)E*4);
  int* bsums   = (int*)alloc(4096);

  hipMemsetAsync(zstart, 0, zbytes, stream);

  const int* srcp = eidx;
  const int* dstp = eidx + E;

  int gE = (E + 255)/256;
  int gN = (N + 255)/256;
  int B  = (N + 1023)/1024;
  int gGemm = (N + 63)/64;
  int gGather = (int)(((size_t)N*64 + 255)/256);

  hist_kernel<<<dim3(gE), dim3(256), 0, stream>>>(dstp, deg, E);
  scan_partial<<<dim3(B), dim3(256), 0, stream>>>(deg, bsums, N);
  scan_bsums<<<dim3(1), dim3(64), 0, stream>>>(bsums, row_start, B, N, E);
  scan_final<<<dim3(B), dim3(256), 0, stream>>>(deg, bsums, row_start, cursor, N);
  dinv_kernel<<<dim3(gN), dim3(256), 0, stream>>>(deg, dinv, N);
  scatter_kernel<<<dim3(gE), dim3(256), 0, stream>>>(srcp, dstp, cursor, csr_src, E);

  // GCN layer 1 (concat input)
  gemm_kernel<<<dim3(gGemm), dim3(256), 0, stream>>>(cnn, morph, g1w, hbuf, N, D, CNNW, MOR);
  gather_kernel<<<dim3(gGather), dim3(256), 0, stream>>>(hbuf, dinv, row_start, csr_src,
      g1b, bn1g, bn1b, (const float*)nullptr, (const float*)nullptr, x1, N, 0);
  // GCN layer 2
  gemm_kernel<<<dim3(gGemm), dim3(256), 0, stream>>>(x1, (const float*)nullptr, g2w, hbuf, N, 128, 128, 0);
  gather_kernel<<<dim3(gGather), dim3(256), 0, stream>>>(hbuf, dinv, row_start, csr_src,
      g2b, bn2g, bn2b, (const float*)nullptr, (const float*)nullptr, x2, N, 0);
  // GCN layer 3 -> writes x_out = x1+x2+x3 in-place into x1
  gemm_kernel<<<dim3(gGemm), dim3(256), 0, stream>>>(x2, (const float*)nullptr, g3w, hbuf, N, 128, 128, 0);
  gather_kernel<<<dim3(gGather), dim3(256), 0, stream>>>(hbuf, dinv, row_start, csr_src,
      g3b, bn3g, bn3b, x1, x2, x1, N, 2);

  // attention gate + segment softmax + pooling
  att_kernel<<<dim3(gGemm), dim3(256), 0, stream>>>(x1, aw1, ab1, aw2, ab2, gate, N);
  segmax_kernel<<<dim3(gN), dim3(256), 0, stream>>>(gate, batch, mg, N);
  expsum_kernel<<<dim3(gN), dim3(256), 0, stream>>>(gate, batch, mg, aex, denom, N);
  pooled_kernel<<<dim3(512), dim3(256), 0, stream>>>(aex, x1, batch, pooled, N);

  classifier_kernel<<<dim3(1), dim3(256), 0, stream>>>(pooled, denom,
      cw1, cb1, c1g, c1b, cw2, cb2, c2g, c2b, cw3, cb3, (float*)d_out);
}

// Round 3
// 1036.028 us; speedup vs baseline: 1.1313x; 1.1313x over previous
//
#include <hip/hip_runtime.h>
#include <hip/hip_bf16.h>

#define EPSV 1e-5f

typedef short short8v __attribute__((ext_vector_type(8)));
typedef float f32x4 __attribute__((ext_vector_type(4)));

// ---------- bf16 helpers (RNE) ----------
__device__ __forceinline__ unsigned short f2bf(float f){
  unsigned u = __float_as_uint(f);
  unsigned r = u + 0x7fffu + ((u >> 16) & 1u);
  return (unsigned short)(r >> 16);
}
__device__ __forceinline__ float bf2f(unsigned short s){
  return __uint_as_float(((unsigned)s) << 16);
}

// ---------- float<->orderable uint encoding for atomic max ----------
__device__ __forceinline__ unsigned enc_f(float f){
  unsigned u = __float_as_uint(f);
  return (u & 0x80000000u) ? ~u : (u | 0x80000000u);
}
__device__ __forceinline__ float dec_f(unsigned k){
  unsigned u = (k & 0x80000000u) ? (k & 0x7fffffffu) : ~k;
  return __uint_as_float(u);
}

// ---------------- degree histogram ----------------
__global__ void hist_kernel(const int* __restrict__ dst, int* __restrict__ deg, int E){
  int i = blockIdx.x*256 + threadIdx.x;
  if (i < E) atomicAdd(&deg[dst[i]], 1);
}

// ---------------- scan ----------------
__global__ void scan_partial(const int* __restrict__ deg, int* __restrict__ bsums, int N){
  __shared__ int sd[256];
  int t = threadIdx.x;
  int base = blockIdx.x*1024 + t*4;
  int s = 0;
  if (base+0 < N) s += deg[base+0];
  if (base+1 < N) s += deg[base+1];
  if (base+2 < N) s += deg[base+2];
  if (base+3 < N) s += deg[base+3];
  sd[t]=s; __syncthreads();
  for (int off=128; off>0; off>>=1){
    if (t<off) sd[t]+=sd[t+off];
    __syncthreads();
  }
  if (t==0) bsums[blockIdx.x]=sd[0];
}

__global__ void scan_bsums(int* bsums, int* row_start, int B, int N, int E){
  if (threadIdx.x==0 && blockIdx.x==0){
    int run=0;
    for (int b=0;b<B;b++){ int v=bsums[b]; bsums[b]=run; run+=v; }
    row_start[N]=E;
  }
}

__global__ void scan_final(const int* __restrict__ deg, const int* __restrict__ bsums,
                           int* __restrict__ row_start, int* __restrict__ cursor, int N){
  __shared__ int sd[256];
  int t=threadIdx.x, b=blockIdx.x;
  int base=b*1024+t*4;
  int v0=0,v1=0,v2=0,v3=0;
  if (base+0<N) v0=deg[base+0];
  if (base+1<N) v1=deg[base+1];
  if (base+2<N) v2=deg[base+2];
  if (base+3<N) v3=deg[base+3];
  int s=v0+v1+v2+v3;
  sd[t]=s; __syncthreads();
  for (int off=1; off<256; off<<=1){
    int x = (t>=off)?sd[t-off]:0;
    __syncthreads();
    sd[t]+=x;
    __syncthreads();
  }
  int excl = sd[t]-s + bsums[b];
  int e0=excl, e1=excl+v0, e2=e1+v1, e3=e2+v2;
  if (base+0<N){ row_start[base+0]=e0; cursor[base+0]=e0; }
  if (base+1<N){ row_start[base+1]=e1; cursor[base+1]=e1; }
  if (base+2<N){ row_start[base+2]=e2; cursor[base+2]=e2; }
  if (base+3<N){ row_start[base+3]=e3; cursor[base+3]=e3; }
}

__global__ void dinv_kernel(const int* __restrict__ deg, float* __restrict__ dinv, int N){
  int i = blockIdx.x*256 + threadIdx.x;
  if (i < N) dinv[i] = rsqrtf((float)deg[i] + 1.0f);
}

__global__ void scatter_kernel(const int* __restrict__ src, const int* __restrict__ dst,
                               int* __restrict__ cursor, int* __restrict__ csr_src, int E){
  int i = blockIdx.x*256 + threadIdx.x;
  if (i < E){
    int d = dst[i];
    int pos = atomicAdd(&cursor[d], 1);
    csr_src[pos] = src[i];
  }
}

// ---------------- W pre-split: W[D x 128] fp32 -> WhiT/WloT [128 x Dpad] bf16 ----------------
__global__ void wsplit_kernel(const float* __restrict__ W, unsigned short* __restrict__ WhiT,
                              unsigned short* __restrict__ WloT, int D, int Dpad){
  int k = blockIdx.x*256 + threadIdx.x;
  int c = blockIdx.y;
  if (k >= Dpad) return;
  float v = (k < D) ? W[(size_t)k*128 + c] : 0.f;
  unsigned short hi = f2bf(v);
  unsigned short lo = f2bf(v - bf2f(hi));
  WhiT[(size_t)c*Dpad + k] = hi;
  WloT[(size_t)c*Dpad + k] = lo;
}

// ---------------- split-bf16 MFMA GEMM: out[N x 128] = concat(xa,xb) @ W ----------------
// BM=128, BN=128, BK=64; 4 waves; LDS 64KB; XOR-swizzled [row][k] bf16 tiles.
__global__ __launch_bounds__(256) void gemm_mfma_kernel(
    const float* __restrict__ xa, const float* __restrict__ xb,
    const unsigned short* __restrict__ WhiT, const unsigned short* __restrict__ WloT,
    float* __restrict__ out, int N, int Da, int Db, int Dpad)
{
  __shared__ unsigned short Ahi[128*64];
  __shared__ unsigned short Alo[128*64];
  __shared__ unsigned short Bhi[128*64];
  __shared__ unsigned short Blo[128*64];

  const int tid  = threadIdx.x;
  const int lane = tid & 63;
  const int wave = tid >> 6;
  const int lr   = lane & 15;   // row/col within 16-tile
  const int kg   = lane >> 4;   // 0..3 k-group
  const int rowBase = blockIdx.x * 128;
  const int D = Da + Db;

  f32x4 acc[2][8];
  #pragma unroll
  for (int s=0;s<2;s++)
    #pragma unroll
    for (int c=0;c<8;c++){ acc[s][c][0]=0.f; acc[s][c][1]=0.f; acc[s][c][2]=0.f; acc[s][c][3]=0.f; }

  // staging coords
  const int arow = tid >> 1;            // 0..127
  const int akseg = (tid & 1) * 32;     // 0/32
  const int Rst = rowBase + arow;
  const int bcol = tid >> 1;            // 0..127
  const int bkseg = (tid & 1) * 32;

  for (int kc = 0; kc < Dpad; kc += 64){
    __syncthreads();
    // ---- stage A (hi/lo split of X rows) ----
    {
      const int gk0 = kc + akseg;
      const bool fastA = (Rst < N) && (gk0 + 32 <= Da);
      const float2* p2 = (const float2*)(xa + (size_t)Rst*Da + gk0);
      const int abase = arow*128 + akseg*2;
      const int aswz = (arow & 7) << 4;
      #pragma unroll
      for (int s=0;s<4;s++){
        alignas(16) unsigned short hi8[8];
        alignas(16) unsigned short lo8[8];
        #pragma unroll
        for (int q=0;q<4;q++){
          float vx, vy;
          if (fastA){
            float2 t2 = p2[s*4+q];
            vx = t2.x; vy = t2.y;
          } else {
            int gk = gk0 + s*8 + 2*q;
            vx = 0.f; vy = 0.f;
            if (Rst < N){
              if (gk < Da) vx = xa[(size_t)Rst*Da + gk];
              else if (gk < D) vx = xb[(size_t)Rst*Db + (gk - Da)];
              if (gk+1 < Da) vy = xa[(size_t)Rst*Da + gk+1];
              else if (gk+1 < D) vy = xb[(size_t)Rst*Db + (gk+1 - Da)];
            }
          }
          unsigned short hx = f2bf(vx); unsigned short hy = f2bf(vy);
          hi8[2*q]   = hx; hi8[2*q+1] = hy;
          lo8[2*q]   = f2bf(vx - bf2f(hx));
          lo8[2*q+1] = f2bf(vy - bf2f(hy));
        }
        int off = (abase + s*16) ^ aswz;
        *(uint4*)((char*)Ahi + off) = *(const uint4*)hi8;
        *(uint4*)((char*)Alo + off) = *(const uint4*)lo8;
      }
    }
    // ---- stage B (pre-split transposed W) ----
    {
      const unsigned short* ph = WhiT + (size_t)bcol*Dpad + kc + bkseg;
      const unsigned short* pl = WloT + (size_t)bcol*Dpad + kc + bkseg;
      const int bbase = bcol*128 + bkseg*2;
      const int bswz = (bcol & 7) << 4;
      #pragma unroll
      for (int s=0;s<4;s++){
        uint4 h = *(const uint4*)(ph + s*8);
        uint4 l = *(const uint4*)(pl + s*8);
        int off = (bbase + s*16) ^ bswz;
        *(uint4*)((char*)Bhi + off) = h;
        *(uint4*)((char*)Blo + off) = l;
      }
    }
    __syncthreads();
    // ---- compute: 2 k-steps of 32, 8 col tiles, 2 row strips ----
    #pragma unroll
    for (int ks=0; ks<2; ks++){
      const int kb = ks*64 + kg*16;           // byte offset of k within 128B row
      const int r0 = wave*32 + lr;
      const int r1 = r0 + 16;
      const int offA0 = (r0*128 + kb) ^ ((r0&7)<<4);
      const int offA1 = (r1*128 + kb) ^ ((r1&7)<<4);
      short8v ah0 = *(const short8v*)((const char*)Ahi + offA0);
      short8v al0 = *(const short8v*)((const char*)Alo + offA0);
      short8v ah1 = *(const short8v*)((const char*)Ahi + offA1);
      short8v al1 = *(const short8v*)((const char*)Alo + offA1);
      #pragma unroll
      for (int ct=0; ct<8; ct++){
        const int c = ct*16 + lr;
        const int offB = (c*128 + kb) ^ ((c&7)<<4);
        short8v bh = *(const short8v*)((const char*)Bhi + offB);
        short8v bl = *(const short8v*)((const char*)Blo + offB);
        acc[0][ct] = __builtin_amdgcn_mfma_f32_16x16x32_bf16(ah0, bh, acc[0][ct], 0,0,0);
        acc[0][ct] = __builtin_amdgcn_mfma_f32_16x16x32_bf16(ah0, bl, acc[0][ct], 0,0,0);
        acc[0][ct] = __builtin_amdgcn_mfma_f32_16x16x32_bf16(al0, bh, acc[0][ct], 0,0,0);
        acc[1][ct] = __builtin_amdgcn_mfma_f32_16x16x32_bf16(ah1, bh, acc[1][ct], 0,0,0);
        acc[1][ct] = __builtin_amdgcn_mfma_f32_16x16x32_bf16(ah1, bl, acc[1][ct], 0,0,0);
        acc[1][ct] = __builtin_amdgcn_mfma_f32_16x16x32_bf16(al1, bh, acc[1][ct], 0,0,0);
      }
    }
  }
  // ---- epilogue: C/D layout col=lane&15, row=(lane>>4)*4+i ----
  const int wrow = rowBase + wave*32;
  #pragma unroll
  for (int strip=0; strip<2; strip++){
    #pragma unroll
    for (int ct=0; ct<8; ct++){
      #pragma unroll
      for (int i=0;i<4;i++){
        int R = wrow + strip*16 + kg*4 + i;
        int C = ct*16 + lr;
        if (R < N) out[(size_t)R*128 + C] = acc[strip][ct][i];
      }
    }
  }
}

// ================= VALU GEMM macros (kept for att_kernel) =================
#define ROWFMA(ACC, XV) \
  ACC.x = __builtin_fmaf((XV), w.x, ACC.x); \
  ACC.y = __builtin_fmaf((XV), w.y, ACC.y); \
  ACC.z = __builtin_fmaf((XV), w.z, ACC.z); \
  ACC.w = __builtin_fmaf((XV), w.w, ACC.w);

#define FMA_STEP(K) { \
  const float4 w   = *(const float4*)(Wl + (K)*128 + wb); \
  const float4 xlo = *(const float4*)(Xl + (K)*64 + r0); \
  const float4 xhi = *(const float4*)(Xl + (K)*64 + r0 + 4); \
  ROWFMA(acc0, xlo.x) ROWFMA(acc1, xlo.y) ROWFMA(acc2, xlo.z) ROWFMA(acc3, xlo.w) \
  ROWFMA(acc4, xhi.x) ROWFMA(acc5, xhi.y) ROWFMA(acc6, xhi.z) ROWFMA(acc7, xhi.w) }

#define GEMM_LOOP \
  const int tid  = threadIdx.x; \
  const int lane = tid & 63; \
  const int wave = tid >> 6; \
  const int half = lane >> 5; \
  const int ff   = lane & 31; \
  const int r0   = wave*16 + half*8; \
  const int wb   = ff << 2; \
  const int srow = tid >> 2; \
  const int skg  = (tid & 3) << 4; \
  const int R_s  = rowBase + srow; \
  float4 acc0={0,0,0,0},acc1={0,0,0,0},acc2={0,0,0,0},acc3={0,0,0,0}; \
  float4 acc4={0,0,0,0},acc5={0,0,0,0},acc6={0,0,0,0},acc7={0,0,0,0}; \
  for (int kc = 0; kc < D; kc += 64){ \
    const int L = (D - kc < 64) ? (D - kc) : 64; \
    __syncthreads(); \
    { \
      const int nf4 = (L*128) >> 2; \
      const float4* Wg = (const float4*)(W + (size_t)kc*128); \
      float4* Wl4 = (float4*)Wl; \
      for (int idx = tid; idx < nf4; idx += 256) Wl4[idx] = Wg[idx]; \
    } \
    if (L == 64 && kc + 64 <= Da){ \
      float4 v0={0,0,0,0},v1={0,0,0,0},v2={0,0,0,0},v3={0,0,0,0}; \
      if (R_s < N){ \
        const float4* xr = (const float4*)(xa + (size_t)R_s*Da + kc + skg); \
        v0 = xr[0]; v1 = xr[1]; v2 = xr[2]; v3 = xr[3]; \
      } \
      Xl[(skg+ 0)*64 + srow]=v0.x; Xl[(skg+ 1)*64 + srow]=v0.y; \
      Xl[(skg+ 2)*64 + srow]=v0.z; Xl[(skg+ 3)*64 + srow]=v0.w; \
      Xl[(skg+ 4)*64 + srow]=v1.x; Xl[(skg+ 5)*64 + srow]=v1.y; \
      Xl[(skg+ 6)*64 + srow]=v1.z; Xl[(skg+ 7)*64 + srow]=v1.w; \
      Xl[(skg+ 8)*64 + srow]=v2.x; Xl[(skg+ 9)*64 + srow]=v2.y; \
      Xl[(skg+10)*64 + srow]=v2.z; Xl[(skg+11)*64 + srow]=v2.w; \
      Xl[(skg+12)*64 + srow]=v3.x; Xl[(skg+13)*64 + srow]=v3.y; \
      Xl[(skg+14)*64 + srow]=v3.z; Xl[(skg+15)*64 + srow]=v3.w; \
    } else if (skg < L){ \
      const int lim = (L - skg < 16) ? (L - skg) : 16; \
      for (int i2=0;i2<lim;i2++){ \
        const int gk = kc + skg + i2; \
        float v = 0.f; \
        if (R_s < N) v = (gk < Da) ? xa[(size_t)R_s*Da + gk] \
                                   : xb[(size_t)R_s*Db + (gk - Da)]; \
        Xl[(skg+i2)*64 + srow] = v; \
      } \
    } \
    __syncthreads(); \
    if (L == 64){ \
      _Pragma("unroll 4") \
      for (int k=0;k<64;k++){ FMA_STEP(k) } \
    } else { \
      for (int k=0;k<L;k++){ FMA_STEP(k) } \
    } \
  }

// attention gate: gate[i] = tanh(x[i]@W + b1) . w2 + b2
__global__ __launch_bounds__(256) void att_kernel(
    const float* __restrict__ xa, const float* __restrict__ W,
    const float* __restrict__ b1, const float* __restrict__ w2,
    const float* __restrict__ b2, float* __restrict__ gate, int N)
{
  __shared__ float Wl[64*128];
  __shared__ float Xl[64*64];
  const int rowBase = blockIdx.x*64;
  const float* xb = xa;  // unused (Db=0)
  const int D = 128, Da = 128, Db = 0;
  GEMM_LOOP
  const int R0 = rowBase + r0;
  const float4 b1v = *(const float4*)(b1 + (ff<<2));
  const float4 w2v = *(const float4*)(w2 + (ff<<2));
  const float bias2 = b2[0];
#define ATT_ROW(ACC, RR) { \
    float p = tanhf(ACC.x + b1v.x)*w2v.x + tanhf(ACC.y + b1v.y)*w2v.y \
            + tanhf(ACC.z + b1v.z)*w2v.z + tanhf(ACC.w + b1v.w)*w2v.w; \
    p += __shfl_xor(p, 1);  p += __shfl_xor(p, 2); \
    p += __shfl_xor(p, 4);  p += __shfl_xor(p, 8); \
    p += __shfl_xor(p, 16); \
    if (ff == 0){ int R = R0 + (RR); if (R < N) gate[R] = p + bias2; } }
  ATT_ROW(acc0,0) ATT_ROW(acc1,1) ATT_ROW(acc2,2) ATT_ROW(acc3,3)
  ATT_ROW(acc4,4) ATT_ROW(acc5,5) ATT_ROW(acc6,6) ATT_ROW(acc7,7)
#undef ATT_ROW
}

// ---------------- gather: one wave per node, float2 per lane ----------------
__global__ void gather_kernel(
    const float* __restrict__ h, const float* __restrict__ dinv,
    const int* __restrict__ row_start, const int* __restrict__ csr_src,
    const float* __restrict__ bias, const float* __restrict__ bng, const float* __restrict__ bnb,
    const float* __restrict__ x1in, const float* __restrict__ x2in,
    float* __restrict__ out, int N, int mode)
{
  int gwid = (blockIdx.x * blockDim.x + threadIdx.x) >> 6;
  int lane = threadIdx.x & 63;
  if (gwid >= N) return;
  const int i = gwid;
  const float di = dinv[i];
  const float2* h2 = (const float2*)h;
  float2 hv = h2[(size_t)i*64 + lane];
  float w0 = di*di;
  float ax = hv.x*w0, ay = hv.y*w0;
  const int s0 = row_start[i], s1 = row_start[i+1];
  for (int base = s0; base < s1; base += 64){
    const int nloc = (s1 - base < 64) ? (s1 - base) : 64;
    int sv = 0; float nv = 0.f;
    if (lane < nloc){ sv = csr_src[base + lane]; nv = dinv[sv]*di; }
    for (int j=0;j<nloc;j++){
      int   sj = __shfl(sv, j);
      float nj = __shfl(nv, j);
      float2 hh = h2[(size_t)sj*64 + lane];
      ax = __builtin_fmaf(hh.x, nj, ax);
      ay = __builtin_fmaf(hh.y, nj, ay);
    }
  }
  const int f0 = lane*2;
  const float bsc = rsqrtf(1.0f + EPSV);
  float sA = bng[f0]*bsc,   sB = bng[f0+1]*bsc;
  float vA = fmaxf(0.f, (ax + bias[f0  ])*sA + bnb[f0  ]);
  float vB = fmaxf(0.f, (ay + bias[f0+1])*sB + bnb[f0+1]);
  if (mode == 2){
    vA += x1in[(size_t)i*128 + f0  ] + x2in[(size_t)i*128 + f0  ];
    vB += x1in[(size_t)i*128 + f0+1] + x2in[(size_t)i*128 + f0+1];
  }
  float2 o; o.x=vA; o.y=vB;
  ((float2*)out)[(size_t)i*64 + lane] = o;
}

// ---------------- segment softmax pieces ----------------
__global__ void segmax_kernel(const float* __restrict__ gate, const int* __restrict__ batch,
                              unsigned* __restrict__ mg, int N){
  __shared__ unsigned sm[8];
  int t = threadIdx.x;
  if (t < 8) sm[t] = 0u;
  __syncthreads();
  int i = blockIdx.x*256 + t;
  if (i < N) atomicMax(&sm[batch[i]], enc_f(gate[i]));
  __syncthreads();
  if (t < 8) atomicMax(&mg[t], sm[t]);
}

__global__ void expsum_kernel(const float* __restrict__ gate, const int* __restrict__ batch,
                              const unsigned* __restrict__ mg, float* __restrict__ aex,
                              float* __restrict__ denom, int N){
  __shared__ float sd[8];
  int t = threadIdx.x;
  if (t < 8) sd[t] = 0.f;
  __syncthreads();
  int i = blockIdx.x*256 + t;
  if (i < N){
    int g = batch[i];
    float m = dec_f(mg[g]);
    float av = expf(gate[i] - m);
    aex[i] = av;
    atomicAdd(&sd[g], av);
  }
  __syncthreads();
  if (t < 8) atomicAdd(&denom[t], sd[t]);
}

__global__ void pooled_kernel(const float* __restrict__ aex, const float* __restrict__ xo,
                              const int* __restrict__ batch, float* __restrict__ pooled, int N){
  int t = threadIdx.x;
  int hlf = t >> 7;
  int f = t & 127;
  int nb = gridDim.x;
  int per = (N + nb - 1)/nb;
  int start = blockIdx.x*per;
  int end = (N < start + per) ? N : (start + per);
  float acc = 0.f; int gcur = -1;
  for (int i = start + hlf; i < end; i += 2){
    int g = batch[i];
    if (g != gcur){
      if (gcur >= 0) atomicAdd(&pooled[gcur*128 + f], acc);
      acc = 0.f; gcur = g;
    }
    acc = __builtin_fmaf(aex[i], xo[(size_t)i*128 + f], acc);
  }
  if (gcur >= 0) atomicAdd(&pooled[gcur*128 + f], acc);
}

// ---------------- classifier head (single block) ----------------
__global__ __launch_bounds__(256) void classifier_kernel(
    const float* __restrict__ pooled, const float* __restrict__ denom,
    const float* __restrict__ w1, const float* __restrict__ b1,
    const float* __restrict__ g1, const float* __restrict__ be1,
    const float* __restrict__ w2, const float* __restrict__ b2,
    const float* __restrict__ g2, const float* __restrict__ be2,
    const float* __restrict__ w3, const float* __restrict__ b3,
    float* __restrict__ outp)
{
  __shared__ float pl[8*128];
  __shared__ float h1[8*256];
  __shared__ float h2l[8*128];
  int t = threadIdx.x;
  for (int idx = t; idx < 1024; idx += 256){
    int g = idx >> 7;
    pl[idx] = pooled[idx] / denom[g];
  }
  __syncthreads();
  {
    float a0=0,a1=0,a2=0,a3=0,a4=0,a5=0,a6=0,a7=0;
    for (int k=0; k<128; k++){
      float w = w1[k*256 + t];
      a0 = __builtin_fmaf(pl[0*128+k], w, a0);
      a1 = __builtin_fmaf(pl[1*128+k], w, a1);
      a2 = __builtin_fmaf(pl[2*128+k], w, a2);
      a3 = __builtin_fmaf(pl[3*128+k], w, a3);
      a4 = __builtin_fmaf(pl[4*128+k], w, a4);
      a5 = __builtin_fmaf(pl[5*128+k], w, a5);
      a6 = __builtin_fmaf(pl[6*128+k], w, a6);
      a7 = __builtin_fmaf(pl[7*128+k], w, a7);
    }
    float s = g1[t]*rsqrtf(1.0f + EPSV);
    float bb = b1[t], tb = be1[t];
    h1[0*256+t] = fmaxf(0.f, (a0+bb)*s + tb);
    h1[1*256+t] = fmaxf(0.f, (a1+bb)*s + tb);
    h1[2*256+t] = fmaxf(0.f, (a2+bb)*s + tb);
    h1[3*256+t] = fmaxf(0.f, (a3+bb)*s + tb);
    h1[4*256+t] = fmaxf(0.f, (a4+bb)*s + tb);
    h1[5*256+t] = fmaxf(0.f, (a5+bb)*s + tb);
    h1[6*256+t] = fmaxf(0.f, (a6+bb)*s + tb);
    h1[7*256+t] = fmaxf(0.f, (a7+bb)*s + tb);
  }
  __syncthreads();
  if (t < 128){
    float a0=0,a1=0,a2=0,a3=0,a4=0,a5=0,a6=0,a7=0;
    for (int k=0; k<256; k++){
      float w = w2[k*128 + t];
      a0 = __builtin_fmaf(h1[0*256+k], w, a0);
      a1 = __builtin_fmaf(h1[1*256+k], w, a1);
      a2 = __builtin_fmaf(h1[2*256+k], w, a2);
      a3 = __builtin_fmaf(h1[3*256+k], w, a3);
      a4 = __builtin_fmaf(h1[4*256+k], w, a4);
      a5 = __builtin_fmaf(h1[5*256+k], w, a5);
      a6 = __builtin_fmaf(h1[6*256+k], w, a6);
      a7 = __builtin_fmaf(h1[7*256+k], w, a7);
    }
    float s = g2[t]*rsqrtf(1.0f + EPSV);
    float bb = b2[t], tb = be2[t];
    h2l[0*128+t] = fmaxf(0.f, (a0+bb)*s + tb);
    h2l[1*128+t] = fmaxf(0.f, (a1+bb)*s + tb);
    h2l[2*128+t] = fmaxf(0.f, (a2+bb)*s + tb);
    h2l[3*128+t] = fmaxf(0.f, (a3+bb)*s + tb);
    h2l[4*128+t] = fmaxf(0.f, (a4+bb)*s + tb);
    h2l[5*128+t] = fmaxf(0.f, (a5+bb)*s + tb);
    h2l[6*128+t] = fmaxf(0.f, (a6+bb)*s + tb);
    h2l[7*128+t] = fmaxf(0.f, (a7+bb)*s + tb);
  }
  __syncthreads();
  if (t < 40){
    int g = t/5, c = t%5;
    float s = 0.f;
    for (int k=0; k<128; k++) s = __builtin_fmaf(h2l[g*128+k], w3[k*5+c], s);
    outp[t] = s + b3[c];
  }
}

extern "C" void kernel_launch(void* const* d_in, const int* in_sizes, int n_in,
                              void* d_out, int out_size, void* d_ws, size_t ws_size,
                              hipStream_t stream)
{
  const float* cnn   = (const float*)d_in[0];
  const float* morph = (const float*)d_in[1];
  const int*   eidx  = (const int*)d_in[2];
  const int*   batch = (const int*)d_in[3];
  const float* g1w = (const float*)d_in[4];
  const float* g1b = (const float*)d_in[5];
  const float* g2w = (const float*)d_in[6];
  const float* g2b = (const float*)d_in[7];
  const float* g3w = (const float*)d_in[8];
  const float* g3b = (const float*)d_in[9];
  const float* bn1g=(const float*)d_in[10], *bn1b=(const float*)d_in[11];
  const float* bn2g=(const float*)d_in[12], *bn2b=(const float*)d_in[13];
  const float* bn3g=(const float*)d_in[14], *bn3b=(const float*)d_in[15];
  const float* aw1=(const float*)d_in[16], *ab1=(const float*)d_in[17];
  const float* aw2=(const float*)d_in[18], *ab2=(const float*)d_in[19];
  const float* cw1=(const float*)d_in[20], *cb1=(const float*)d_in[21];
  const float* c1g=(const float*)d_in[22], *c1b=(const float*)d_in[23];
  const float* cw2=(const float*)d_in[24], *cb2=(const float*)d_in[25];
  const float* c2g=(const float*)d_in[26], *c2b=(const float*)d_in[27];
  const float* cw3=(const float*)d_in[28], *cb3=(const float*)d_in[29];

  const int N = in_sizes[3];
  const int E = in_sizes[2] / 2;
  const int CNNW = in_sizes[0] / N;   // 768
  const int MOR  = in_sizes[1] / N;   // 6
  const int D = CNNW + MOR;           // 774
  const int Dpad1 = ((D + 63)/64)*64; // 832

  char* p = (char*)d_ws;
  auto alloc = [&](size_t bytes)->char* {
    char* r = p; p += (bytes + 255) & ~(size_t)255; return r;
  };
  float* hbuf  = (float*)alloc((size_t)N*128*4);
  float* x1    = (float*)alloc((size_t)N*128*4);
  float* x2    = (float*)alloc((size_t)N*128*4);
  float* dinv  = (float*)alloc((size_t)N*4);
  float* gate  = (float*)alloc((size_t)N*4);
  float* aex   = (float*)alloc((size_t)N*4);
  char* zstart = p;
  int* deg      = (int*)alloc((size_t)N*4);
  unsigned* mg  = (unsigned*)alloc(8*4);
  float* denom  = (float*)alloc(8*4);
  float* pooled = (float*)alloc(8*128*4);
  size_t zbytes = (size_t)(p - zstart);
  int* row_start=(int*)alloc((size_t)(N+1)*4);
  int* cursor  = (int*)alloc((size_t)N*4);
  int* csr_src = (int*)alloc((size_t)E*4);
  int* bsums   = (int*)alloc(4096);
  unsigned short* w1hiT = (unsigned short*)alloc((size_t)128*Dpad1*2);
  unsigned short* w1loT = (unsigned short*)alloc((size_t)128*Dpad1*2);
  unsigned short* w2hiT = (unsigned short*)alloc((size_t)128*128*2);
  unsigned short* w2loT = (unsigned short*)alloc((size_t)128*128*2);
  unsigned short* w3hiT = (unsigned short*)alloc((size_t)128*128*2);
  unsigned short* w3loT = (unsigned short*)alloc((size_t)128*128*2);

  hipMemsetAsync(zstart, 0, zbytes, stream);

  const int* srcp = eidx;
  const int* dstp = eidx + E;

  int gE = (E + 255)/256;
  int gN = (N + 255)/256;
  int B  = (N + 1023)/1024;
  int gMfma = (N + 127)/128;
  int gAtt  = (N + 63)/64;
  int gGather = (int)(((size_t)N*64 + 255)/256);

  // CSR build
  hist_kernel<<<dim3(gE), dim3(256), 0, stream>>>(dstp, deg, E);
  scan_partial<<<dim3(B), dim3(256), 0, stream>>>(deg, bsums, N);
  scan_bsums<<<dim3(1), dim3(64), 0, stream>>>(bsums, row_start, B, N, E);
  scan_final<<<dim3(B), dim3(256), 0, stream>>>(deg, bsums, row_start, cursor, N);
  dinv_kernel<<<dim3(gN), dim3(256), 0, stream>>>(deg, dinv, N);
  scatter_kernel<<<dim3(gE), dim3(256), 0, stream>>>(srcp, dstp, cursor, csr_src, E);

  // weight pre-split (hi/lo bf16, transposed)
  wsplit_kernel<<<dim3((Dpad1+255)/256, 128), dim3(256), 0, stream>>>(g1w, w1hiT, w1loT, D, Dpad1);
  wsplit_kernel<<<dim3(1, 128), dim3(256), 0, stream>>>(g2w, w2hiT, w2loT, 128, 128);
  wsplit_kernel<<<dim3(1, 128), dim3(256), 0, stream>>>(g3w, w3hiT, w3loT, 128, 128);

  // GCN layer 1 (concat input)
  gemm_mfma_kernel<<<dim3(gMfma), dim3(256), 0, stream>>>(cnn, morph, w1hiT, w1loT, hbuf, N, CNNW, MOR, Dpad1);
  gather_kernel<<<dim3(gGather), dim3(256), 0, stream>>>(hbuf, dinv, row_start, csr_src,
      g1b, bn1g, bn1b, (const float*)nullptr, (const float*)nullptr, x1, N, 0);
  // GCN layer 2
  gemm_mfma_kernel<<<dim3(gMfma), dim3(256), 0, stream>>>(x1, (const float*)nullptr, w2hiT, w2loT, hbuf, N, 128, 0, 128);
  gather_kernel<<<dim3(gGather), dim3(256), 0, stream>>>(hbuf, dinv, row_start, csr_src,
      g2b, bn2g, bn2b, (const float*)nullptr, (const float*)nullptr, x2, N, 0);
  // GCN layer 3 -> x_out = x1+x2+x3 into x1
  gemm_mfma_kernel<<<dim3(gMfma), dim3(256), 0, stream>>>(x2, (const float*)nullptr, w3hiT, w3loT, hbuf, N, 128, 0, 128);
  gather_kernel<<<dim3(gGather), dim3(256), 0, stream>>>(hbuf, dinv, row_start, csr_src,
      g3b, bn3g, bn3b, x1, x2, x1, N, 2);

  // attention gate + segment softmax + pooling
  att_kernel<<<dim3(gAtt), dim3(256), 0, stream>>>(x1, aw1, ab1, aw2, ab2, gate, N);
  segmax_kernel<<<dim3(gN), dim3(256), 0, stream>>>(gate, batch, mg, N);
  expsum_kernel<<<dim3(gN), dim3(256), 0, stream>>>(gate, batch, mg, aex, denom, N);
  pooled_kernel<<<dim3(512), dim3(256), 0, stream>>>(aex, x1, batch, pooled, N);

  classifier_kernel<<<dim3(1), dim3(256), 0, stream>>>(pooled, denom,
      cw1, cb1, c1g, c1b, cw2, cb2, c2g, c2b, cw3, cb3, (float*)d_out);
}

// Round 4
// 750.578 us; speedup vs baseline: 1.5615x; 1.3803x over previous
//
#include <hip/hip_runtime.h>
#include <hip/hip_bf16.h>

#define EPSV 1e-5f

typedef short short8v __attribute__((ext_vector_type(8)));
typedef float f32x4 __attribute__((ext_vector_type(4)));

// ---------- bf16 helpers ----------
__device__ __forceinline__ unsigned short f2bf(float f){ // RNE
  unsigned u = __float_as_uint(f);
  unsigned r = u + 0x7fffu + ((u >> 16) & 1u);
  return (unsigned short)(r >> 16);
}
__device__ __forceinline__ unsigned pk2bf(float x, float y){
  return (unsigned)f2bf(x) | ((unsigned)f2bf(y) << 16);
}
__device__ __forceinline__ float bflo(unsigned u){ return __uint_as_float(u << 16); }
__device__ __forceinline__ float bfhi(unsigned u){ return __uint_as_float(u & 0xffff0000u); }

// ---------- float<->orderable uint encoding for atomic max ----------
__device__ __forceinline__ unsigned enc_f(float f){
  unsigned u = __float_as_uint(f);
  return (u & 0x80000000u) ? ~u : (u | 0x80000000u);
}
__device__ __forceinline__ float dec_f(unsigned k){
  unsigned u = (k & 0x80000000u) ? (k & 0x7fffffffu) : ~k;
  return __uint_as_float(u);
}

// ---------------- degree histogram ----------------
__global__ void hist_kernel(const int* __restrict__ dst, int* __restrict__ deg, int E){
  int i = blockIdx.x*256 + threadIdx.x;
  if (i < E) atomicAdd(&deg[dst[i]], 1);
}

// ---------------- scan ----------------
__global__ void scan_partial(const int* __restrict__ deg, int* __restrict__ bsums, int N){
  __shared__ int sd[256];
  int t = threadIdx.x;
  int base = blockIdx.x*1024 + t*4;
  int s = 0;
  if (base+0 < N) s += deg[base+0];
  if (base+1 < N) s += deg[base+1];
  if (base+2 < N) s += deg[base+2];
  if (base+3 < N) s += deg[base+3];
  sd[t]=s; __syncthreads();
  for (int off=128; off>0; off>>=1){
    if (t<off) sd[t]+=sd[t+off];
    __syncthreads();
  }
  if (t==0) bsums[blockIdx.x]=sd[0];
}

__global__ void scan_bsums(int* bsums, int* row_start, int B, int N, int E){
  if (threadIdx.x==0 && blockIdx.x==0){
    int run=0;
    for (int b=0;b<B;b++){ int v=bsums[b]; bsums[b]=run; run+=v; }
    row_start[N]=E;
  }
}

__global__ void scan_final(const int* __restrict__ deg, const int* __restrict__ bsums,
                           int* __restrict__ row_start, int* __restrict__ cursor, int N){
  __shared__ int sd[256];
  int t=threadIdx.x, b=blockIdx.x;
  int base=b*1024+t*4;
  int v0=0,v1=0,v2=0,v3=0;
  if (base+0<N) v0=deg[base+0];
  if (base+1<N) v1=deg[base+1];
  if (base+2<N) v2=deg[base+2];
  if (base+3<N) v3=deg[base+3];
  int s=v0+v1+v2+v3;
  sd[t]=s; __syncthreads();
  for (int off=1; off<256; off<<=1){
    int x = (t>=off)?sd[t-off]:0;
    __syncthreads();
    sd[t]+=x;
    __syncthreads();
  }
  int excl = sd[t]-s + bsums[b];
  int e0=excl, e1=excl+v0, e2=e1+v1, e3=e2+v2;
  if (base+0<N){ row_start[base+0]=e0; cursor[base+0]=e0; }
  if (base+1<N){ row_start[base+1]=e1; cursor[base+1]=e1; }
  if (base+2<N){ row_start[base+2]=e2; cursor[base+2]=e2; }
  if (base+3<N){ row_start[base+3]=e3; cursor[base+3]=e3; }
}

__global__ void dinv_kernel(const int* __restrict__ deg, float* __restrict__ dinv, int N){
  int i = blockIdx.x*256 + threadIdx.x;
  if (i < N) dinv[i] = rsqrtf((float)deg[i] + 1.0f);
}

__global__ void scatter_kernel(const int* __restrict__ src, const int* __restrict__ dst,
                               int* __restrict__ cursor, int* __restrict__ csr_src, int E){
  int i = blockIdx.x*256 + threadIdx.x;
  if (i < E){
    int d = dst[i];
    int pos = atomicAdd(&cursor[d], 1);
    csr_src[pos] = src[i];
  }
}

// ---------------- W pre-convert: W[D x 128] fp32 -> WT [128 x Dpad] bf16 ----------------
__global__ void wsplit_kernel(const float* __restrict__ W, unsigned short* __restrict__ WT,
                              int D, int Dpad){
  int k = blockIdx.x*256 + threadIdx.x;
  int c = blockIdx.y;
  if (k >= Dpad) return;
  float v = (k < D) ? W[(size_t)k*128 + c] : 0.f;
  WT[(size_t)c*Dpad + k] = f2bf(v);
}

// ---------------- bf16 MFMA GEMM: hb[N x 128](bf16) = concat(xa,xb) @ W ----------------
// BM=128, BN=128, BK=64; 4 waves; LDS 32KB; XOR-swizzled [row][k] bf16 tiles.
__global__ __launch_bounds__(256, 4) void gemm_mfma_kernel(
    const float* __restrict__ xa, const float* __restrict__ xb,
    const unsigned short* __restrict__ WT,
    unsigned short* __restrict__ outb, int N, int Da, int Db, int Dpad)
{
  __shared__ unsigned short Abf[128*64];
  __shared__ unsigned short Bbf[128*64];

  const int tid  = threadIdx.x;
  const int lane = tid & 63;
  const int wave = tid >> 6;
  const int lr   = lane & 15;   // row/col within 16-tile
  const int kg   = lane >> 4;   // 0..3 k-group
  const int rowBase = blockIdx.x * 128;
  const int D = Da + Db;

  f32x4 acc[2][8];
  #pragma unroll
  for (int s=0;s<2;s++)
    #pragma unroll
    for (int c=0;c<8;c++){ acc[s][c][0]=0.f; acc[s][c][1]=0.f; acc[s][c][2]=0.f; acc[s][c][3]=0.f; }

  const int arow = tid >> 1;            // 0..127
  const int akseg = (tid & 1) * 32;     // 0/32 (k elems)
  const int Rst = rowBase + arow;

  for (int kc = 0; kc < Dpad; kc += 64){
    __syncthreads();
    // ---- stage A: 32 fp32 -> 32 bf16 per thread ----
    {
      const int gk0 = kc + akseg;
      const bool fastA = (Rst < N) && (gk0 + 32 <= Da);
      const int abase = arow*128 + akseg*2;     // byte offset
      const int aswz = (arow & 7) << 4;
      if (fastA){
        const float4* p4 = (const float4*)(xa + (size_t)Rst*Da + gk0);
        #pragma unroll
        for (int s=0;s<4;s++){
          float4 va = p4[2*s];
          float4 vb = p4[2*s+1];
          unsigned u[4];
          u[0] = pk2bf(va.x, va.y); u[1] = pk2bf(va.z, va.w);
          u[2] = pk2bf(vb.x, vb.y); u[3] = pk2bf(vb.z, vb.w);
          int off = (abase + s*16) ^ aswz;
          *(uint4*)((char*)Abf + off) = *(const uint4*)u;
        }
      } else {
        #pragma unroll
        for (int s=0;s<4;s++){
          unsigned u[4];
          #pragma unroll
          for (int q=0;q<4;q++){
            int gk = gk0 + s*8 + 2*q;
            float vx=0.f, vy=0.f;
            if (Rst < N){
              if (gk < Da) vx = xa[(size_t)Rst*Da + gk];
              else if (gk < D) vx = xb[(size_t)Rst*Db + (gk - Da)];
              if (gk+1 < Da) vy = xa[(size_t)Rst*Da + gk+1];
              else if (gk+1 < D) vy = xb[(size_t)Rst*Db + (gk+1 - Da)];
            }
            u[q] = pk2bf(vx, vy);
          }
          int off = (abase + s*16) ^ aswz;
          *(uint4*)((char*)Abf + off) = *(const uint4*)u;
        }
      }
    }
    // ---- stage B: pre-converted transposed W (bf16) ----
    {
      const unsigned short* ph = WT + (size_t)(tid>>1)*Dpad + kc + akseg;
      const int bbase = (tid>>1)*128 + akseg*2;
      const int bswz = ((tid>>1) & 7) << 4;
      #pragma unroll
      for (int s=0;s<4;s++){
        uint4 h = *(const uint4*)(ph + s*8);
        int off = (bbase + s*16) ^ bswz;
        *(uint4*)((char*)Bbf + off) = h;
      }
    }
    __syncthreads();
    // ---- compute: 2 k-steps of 32 ----
    #pragma unroll
    for (int ks=0; ks<2; ks++){
      const int kb = ks*64 + kg*16;
      const int r0 = wave*32 + lr;
      const int r1 = r0 + 16;
      const int offA0 = (r0*128 + kb) ^ ((r0&7)<<4);
      const int offA1 = (r1*128 + kb) ^ ((r1&7)<<4);
      short8v a0 = *(const short8v*)((const char*)Abf + offA0);
      short8v a1 = *(const short8v*)((const char*)Abf + offA1);
      #pragma unroll
      for (int ct=0; ct<8; ct++){
        const int c = ct*16 + lr;
        const int offB = (c*128 + kb) ^ ((c&7)<<4);
        short8v b = *(const short8v*)((const char*)Bbf + offB);
        acc[0][ct] = __builtin_amdgcn_mfma_f32_16x16x32_bf16(a0, b, acc[0][ct], 0,0,0);
        acc[1][ct] = __builtin_amdgcn_mfma_f32_16x16x32_bf16(a1, b, acc[1][ct], 0,0,0);
      }
    }
  }
  // ---- epilogue: C/D layout col=lane&15, row=(lane>>4)*4+i; write bf16 ----
  const int wrow = rowBase + wave*32;
  #pragma unroll
  for (int strip=0; strip<2; strip++){
    #pragma unroll
    for (int ct=0; ct<8; ct++){
      #pragma unroll
      for (int i=0;i<4;i++){
        int R = wrow + strip*16 + kg*4 + i;
        int C = ct*16 + lr;
        if (R < N) outb[(size_t)R*128 + C] = f2bf(acc[strip][ct][i]);
      }
    }
  }
}

// ================= VALU GEMM macros (att_kernel) =================
#define ROWFMA(ACC, XV) \
  ACC.x = __builtin_fmaf((XV), w.x, ACC.x); \
  ACC.y = __builtin_fmaf((XV), w.y, ACC.y); \
  ACC.z = __builtin_fmaf((XV), w.z, ACC.z); \
  ACC.w = __builtin_fmaf((XV), w.w, ACC.w);

#define FMA_STEP(K) { \
  const float4 w   = *(const float4*)(Wl + (K)*128 + wb); \
  const float4 xlo = *(const float4*)(Xl + (K)*64 + r0); \
  const float4 xhi = *(const float4*)(Xl + (K)*64 + r0 + 4); \
  ROWFMA(acc0, xlo.x) ROWFMA(acc1, xlo.y) ROWFMA(acc2, xlo.z) ROWFMA(acc3, xlo.w) \
  ROWFMA(acc4, xhi.x) ROWFMA(acc5, xhi.y) ROWFMA(acc6, xhi.z) ROWFMA(acc7, xhi.w) }

#define GEMM_LOOP \
  const int tid  = threadIdx.x; \
  const int lane = tid & 63; \
  const int wave = tid >> 6; \
  const int half = lane >> 5; \
  const int ff   = lane & 31; \
  const int r0   = wave*16 + half*8; \
  const int wb   = ff << 2; \
  const int srow = tid >> 2; \
  const int skg  = (tid & 3) << 4; \
  const int R_s  = rowBase + srow; \
  float4 acc0={0,0,0,0},acc1={0,0,0,0},acc2={0,0,0,0},acc3={0,0,0,0}; \
  float4 acc4={0,0,0,0},acc5={0,0,0,0},acc6={0,0,0,0},acc7={0,0,0,0}; \
  for (int kc = 0; kc < D; kc += 64){ \
    const int L = (D - kc < 64) ? (D - kc) : 64; \
    __syncthreads(); \
    { \
      const int nf4 = (L*128) >> 2; \
      const float4* Wg = (const float4*)(W + (size_t)kc*128); \
      float4* Wl4 = (float4*)Wl; \
      for (int idx = tid; idx < nf4; idx += 256) Wl4[idx] = Wg[idx]; \
    } \
    if (L == 64 && kc + 64 <= Da){ \
      float4 v0={0,0,0,0},v1={0,0,0,0},v2={0,0,0,0},v3={0,0,0,0}; \
      if (R_s < N){ \
        const float4* xr = (const float4*)(xa + (size_t)R_s*Da + kc + skg); \
        v0 = xr[0]; v1 = xr[1]; v2 = xr[2]; v3 = xr[3]; \
      } \
      Xl[(skg+ 0)*64 + srow]=v0.x; Xl[(skg+ 1)*64 + srow]=v0.y; \
      Xl[(skg+ 2)*64 + srow]=v0.z; Xl[(skg+ 3)*64 + srow]=v0.w; \
      Xl[(skg+ 4)*64 + srow]=v1.x; Xl[(skg+ 5)*64 + srow]=v1.y; \
      Xl[(skg+ 6)*64 + srow]=v1.z; Xl[(skg+ 7)*64 + srow]=v1.w; \
      Xl[(skg+ 8)*64 + srow]=v2.x; Xl[(skg+ 9)*64 + srow]=v2.y; \
      Xl[(skg+10)*64 + srow]=v2.z; Xl[(skg+11)*64 + srow]=v2.w; \
      Xl[(skg+12)*64 + srow]=v3.x; Xl[(skg+13)*64 + srow]=v3.y; \
      Xl[(skg+14)*64 + srow]=v3.z; Xl[(skg+15)*64 + srow]=v3.w; \
    } else if (skg < L){ \
      const int lim = (L - skg < 16) ? (L - skg) : 16; \
      for (int i2=0;i2<lim;i2++){ \
        const int gk = kc + skg + i2; \
        float v = 0.f; \
        if (R_s < N) v = (gk < Da) ? xa[(size_t)R_s*Da + gk] \
                                   : xb[(size_t)R_s*Db + (gk - Da)]; \
        Xl[(skg+i2)*64 + srow] = v; \
      } \
    } \
    __syncthreads(); \
    if (L == 64){ \
      _Pragma("unroll 4") \
      for (int k=0;k<64;k++){ FMA_STEP(k) } \
    } else { \
      for (int k=0;k<L;k++){ FMA_STEP(k) } \
    } \
  }

// attention gate: gate[i] = tanh(x[i]@W + b1) . w2 + b2
__global__ __launch_bounds__(256) void att_kernel(
    const float* __restrict__ xa, const float* __restrict__ W,
    const float* __restrict__ b1, const float* __restrict__ w2,
    const float* __restrict__ b2, float* __restrict__ gate, int N)
{
  __shared__ float Wl[64*128];
  __shared__ float Xl[64*64];
  const int rowBase = blockIdx.x*64;
  const float* xb = xa;  // unused (Db=0)
  const int D = 128, Da = 128, Db = 0;
  GEMM_LOOP
  const int R0 = rowBase + r0;
  const float4 b1v = *(const float4*)(b1 + (ff<<2));
  const float4 w2v = *(const float4*)(w2 + (ff<<2));
  const float bias2 = b2[0];
#define ATT_ROW(ACC, RR) { \
    float p = tanhf(ACC.x + b1v.x)*w2v.x + tanhf(ACC.y + b1v.y)*w2v.y \
            + tanhf(ACC.z + b1v.z)*w2v.z + tanhf(ACC.w + b1v.w)*w2v.w; \
    p += __shfl_xor(p, 1);  p += __shfl_xor(p, 2); \
    p += __shfl_xor(p, 4);  p += __shfl_xor(p, 8); \
    p += __shfl_xor(p, 16); \
    if (ff == 0){ int R = R0 + (RR); if (R < N) gate[R] = p + bias2; } }
  ATT_ROW(acc0,0) ATT_ROW(acc1,1) ATT_ROW(acc2,2) ATT_ROW(acc3,3)
  ATT_ROW(acc4,4) ATT_ROW(acc5,5) ATT_ROW(acc6,6) ATT_ROW(acc7,7)
#undef ATT_ROW
}

// ---------------- gather: 16 lanes per node, 8 bf16 feats per lane ----------------
// mode 0: out = relu(bn(agg + bias));  mode 2: out = x1in + x2in + relu(bn(agg + bias))
__global__ __launch_bounds__(256) void gather_kernel(
    const unsigned short* __restrict__ hb, const float* __restrict__ dinv,
    const int* __restrict__ row_start, const int* __restrict__ csr_src,
    const float* __restrict__ bias, const float* __restrict__ bng, const float* __restrict__ bnb,
    const float* __restrict__ x1in, const float* __restrict__ x2in,
    float* __restrict__ out, int N, int mode)
{
  const int grp = (blockIdx.x * 256 + threadIdx.x) >> 4;   // node id
  const int sl  = threadIdx.x & 15;
  if (grp >= N) return;
  const int i = grp;
  const float di = dinv[i];

  float a[8];
  {
    uint4 u = *(const uint4*)(hb + (size_t)i*128 + sl*8);
    float w0 = di*di;
    a[0] = bflo(u.x)*w0; a[1] = bfhi(u.x)*w0;
    a[2] = bflo(u.y)*w0; a[3] = bfhi(u.y)*w0;
    a[4] = bflo(u.z)*w0; a[5] = bfhi(u.z)*w0;
    a[6] = bflo(u.w)*w0; a[7] = bfhi(u.w)*w0;
  }
  const int s0 = row_start[i], s1 = row_start[i+1];
  for (int base = s0; base < s1; base += 16){
    const int nloc = (s1 - base < 16) ? (s1 - base) : 16;
    int sv = 0; float nv = 0.f;
    if (sl < nloc){ sv = csr_src[base + sl]; nv = dinv[sv]*di; }
    for (int j=0;j<nloc;j++){
      int   sj = __shfl(sv, j, 16);
      float nj = __shfl(nv, j, 16);
      uint4 u = *(const uint4*)(hb + (size_t)sj*128 + sl*8);
      a[0] = __builtin_fmaf(bflo(u.x), nj, a[0]);
      a[1] = __builtin_fmaf(bfhi(u.x), nj, a[1]);
      a[2] = __builtin_fmaf(bflo(u.y), nj, a[2]);
      a[3] = __builtin_fmaf(bfhi(u.y), nj, a[3]);
      a[4] = __builtin_fmaf(bflo(u.z), nj, a[4]);
      a[5] = __builtin_fmaf(bfhi(u.z), nj, a[5]);
      a[6] = __builtin_fmaf(bflo(u.w), nj, a[6]);
      a[7] = __builtin_fmaf(bfhi(u.w), nj, a[7]);
    }
  }
  const int f0 = sl*8;
  const float bsc = rsqrtf(1.0f + EPSV);
  float4 bi0 = *(const float4*)(bias + f0);
  float4 bi1 = *(const float4*)(bias + f0 + 4);
  float4 g0 = *(const float4*)(bng + f0);
  float4 g1 = *(const float4*)(bng + f0 + 4);
  float4 be0 = *(const float4*)(bnb + f0);
  float4 be1 = *(const float4*)(bnb + f0 + 4);
  float v[8];
  v[0] = fmaxf(0.f, (a[0]+bi0.x)*(g0.x*bsc) + be0.x);
  v[1] = fmaxf(0.f, (a[1]+bi0.y)*(g0.y*bsc) + be0.y);
  v[2] = fmaxf(0.f, (a[2]+bi0.z)*(g0.z*bsc) + be0.z);
  v[3] = fmaxf(0.f, (a[3]+bi0.w)*(g0.w*bsc) + be0.w);
  v[4] = fmaxf(0.f, (a[4]+bi1.x)*(g1.x*bsc) + be1.x);
  v[5] = fmaxf(0.f, (a[5]+bi1.y)*(g1.y*bsc) + be1.y);
  v[6] = fmaxf(0.f, (a[6]+bi1.z)*(g1.z*bsc) + be1.z);
  v[7] = fmaxf(0.f, (a[7]+bi1.w)*(g1.w*bsc) + be1.w);
  if (mode == 2){
    float4 p0 = *(const float4*)(x1in + (size_t)i*128 + f0);
    float4 p1 = *(const float4*)(x1in + (size_t)i*128 + f0 + 4);
    float4 q0 = *(const float4*)(x2in + (size_t)i*128 + f0);
    float4 q1 = *(const float4*)(x2in + (size_t)i*128 + f0 + 4);
    v[0]+=p0.x+q0.x; v[1]+=p0.y+q0.y; v[2]+=p0.z+q0.z; v[3]+=p0.w+q0.w;
    v[4]+=p1.x+q1.x; v[5]+=p1.y+q1.y; v[6]+=p1.z+q1.z; v[7]+=p1.w+q1.w;
  }
  float4 o0; o0.x=v[0]; o0.y=v[1]; o0.z=v[2]; o0.w=v[3];
  float4 o1; o1.x=v[4]; o1.y=v[5]; o1.z=v[6]; o1.w=v[7];
  *(float4*)(out + (size_t)i*128 + f0)     = o0;
  *(float4*)(out + (size_t)i*128 + f0 + 4) = o1;
}

// ---------------- segment softmax pieces ----------------
__global__ void segmax_kernel(const float* __restrict__ gate, const int* __restrict__ batch,
                              unsigned* __restrict__ mg, int N){
  __shared__ unsigned sm[8];
  int t = threadIdx.x;
  if (t < 8) sm[t] = 0u;
  __syncthreads();
  int i = blockIdx.x*256 + t;
  if (i < N) atomicMax(&sm[batch[i]], enc_f(gate[i]));
  __syncthreads();
  if (t < 8) atomicMax(&mg[t], sm[t]);
}

__global__ void expsum_kernel(const float* __restrict__ gate, const int* __restrict__ batch,
                              const unsigned* __restrict__ mg, float* __restrict__ aex,
                              float* __restrict__ denom, int N){
  __shared__ float sd[8];
  int t = threadIdx.x;
  if (t < 8) sd[t] = 0.f;
  __syncthreads();
  int i = blockIdx.x*256 + t;
  if (i < N){
    int g = batch[i];
    float m = dec_f(mg[g]);
    float av = expf(gate[i] - m);
    aex[i] = av;
    atomicAdd(&sd[g], av);
  }
  __syncthreads();
  if (t < 8) atomicAdd(&denom[t], sd[t]);
}

__global__ void pooled_kernel(const float* __restrict__ aex, const float* __restrict__ xo,
                              const int* __restrict__ batch, float* __restrict__ pooled, int N){
  int t = threadIdx.x;
  int hlf = t >> 7;
  int f = t & 127;
  int nb = gridDim.x;
  int per = (N + nb - 1)/nb;
  int start = blockIdx.x*per;
  int end = (N < start + per) ? N : (start + per);
  float acc = 0.f; int gcur = -1;
  for (int i = start + hlf; i < end; i += 2){
    int g = batch[i];
    if (g != gcur){
      if (gcur >= 0) atomicAdd(&pooled[gcur*128 + f], acc);
      acc = 0.f; gcur = g;
    }
    acc = __builtin_fmaf(aex[i], xo[(size_t)i*128 + f], acc);
  }
  if (gcur >= 0) atomicAdd(&pooled[gcur*128 + f], acc);
}

// ---------------- classifier head (single block) ----------------
__global__ __launch_bounds__(256) void classifier_kernel(
    const float* __restrict__ pooled, const float* __restrict__ denom,
    const float* __restrict__ w1, const float* __restrict__ b1,
    const float* __restrict__ g1, const float* __restrict__ be1,
    const float* __restrict__ w2, const float* __restrict__ b2,
    const float* __restrict__ g2, const float* __restrict__ be2,
    const float* __restrict__ w3, const float* __restrict__ b3,
    float* __restrict__ outp)
{
  __shared__ float pl[8*128];
  __shared__ float h1[8*256];
  __shared__ float h2l[8*128];
  int t = threadIdx.x;
  for (int idx = t; idx < 1024; idx += 256){
    int g = idx >> 7;
    pl[idx] = pooled[idx] / denom[g];
  }
  __syncthreads();
  {
    float a0=0,a1=0,a2=0,a3=0,a4=0,a5=0,a6=0,a7=0;
    for (int k=0; k<128; k++){
      float w = w1[k*256 + t];
      a0 = __builtin_fmaf(pl[0*128+k], w, a0);
      a1 = __builtin_fmaf(pl[1*128+k], w, a1);
      a2 = __builtin_fmaf(pl[2*128+k], w, a2);
      a3 = __builtin_fmaf(pl[3*128+k], w, a3);
      a4 = __builtin_fmaf(pl[4*128+k], w, a4);
      a5 = __builtin_fmaf(pl[5*128+k], w, a5);
      a6 = __builtin_fmaf(pl[6*128+k], w, a6);
      a7 = __builtin_fmaf(pl[7*128+k], w, a7);
    }
    float s = g1[t]*rsqrtf(1.0f + EPSV);
    float bb = b1[t], tb = be1[t];
    h1[0*256+t] = fmaxf(0.f, (a0+bb)*s + tb);
    h1[1*256+t] = fmaxf(0.f, (a1+bb)*s + tb);
    h1[2*256+t] = fmaxf(0.f, (a2+bb)*s + tb);
    h1[3*256+t] = fmaxf(0.f, (a3+bb)*s + tb);
    h1[4*256+t] = fmaxf(0.f, (a4+bb)*s + tb);
    h1[5*256+t] = fmaxf(0.f, (a5+bb)*s + tb);
    h1[6*256+t] = fmaxf(0.f, (a6+bb)*s + tb);
    h1[7*256+t] = fmaxf(0.f, (a7+bb)*s + tb);
  }
  __syncthreads();
  if (t < 128){
    float a0=0,a1=0,a2=0,a3=0,a4=0,a5=0,a6=0,a7=0;
    for (int k=0; k<256; k++){
      float w = w2[k*128 + t];
      a0 = __builtin_fmaf(h1[0*256+k], w, a0);
      a1 = __builtin_fmaf(h1[1*256+k], w, a1);
      a2 = __builtin_fmaf(h1[2*256+k], w, a2);
      a3 = __builtin_fmaf(h1[3*256+k], w, a3);
      a4 = __builtin_fmaf(h1[4*256+k], w, a4);
      a5 = __builtin_fmaf(h1[5*256+k], w, a5);
      a6 = __builtin_fmaf(h1[6*256+k], w, a6);
      a7 = __builtin_fmaf(h1[7*256+k], w, a7);
    }
    float s = g2[t]*rsqrtf(1.0f + EPSV);
    float bb = b2[t], tb = be2[t];
    h2l[0*128+t] = fmaxf(0.f, (a0+bb)*s + tb);
    h2l[1*128+t] = fmaxf(0.f, (a1+bb)*s + tb);
    h2l[2*128+t] = fmaxf(0.f, (a2+bb)*s + tb);
    h2l[3*128+t] = fmaxf(0.f, (a3+bb)*s + tb);
    h2l[4*128+t] = fmaxf(0.f, (a4+bb)*s + tb);
    h2l[5*128+t] = fmaxf(0.f, (a5+bb)*s + tb);
    h2l[6*128+t] = fmaxf(0.f, (a6+bb)*s + tb);
    h2l[7*128+t] = fmaxf(0.f, (a7+bb)*s + tb);
  }
  __syncthreads();
  if (t < 40){
    int g = t/5, c = t%5;
    float s = 0.f;
    for (int k=0; k<128; k++) s = __builtin_fmaf(h2l[g*128+k], w3[k*5+c], s);
    outp[t] = s + b3[c];
  }
}

extern "C" void kernel_launch(void* const* d_in, const int* in_sizes, int n_in,
                              void* d_out, int out_size, void* d_ws, size_t ws_size,
                              hipStream_t stream)
{
  const float* cnn   = (const float*)d_in[0];
  const float* morph = (const float*)d_in[1];
  const int*   eidx  = (const int*)d_in[2];
  const int*   batch = (const int*)d_in[3];
  const float* g1w = (const float*)d_in[4];
  const float* g1b = (const float*)d_in[5];
  const float* g2w = (const float*)d_in[6];
  const float* g2b = (const float*)d_in[7];
  const float* g3w = (const float*)d_in[8];
  const float* g3b = (const float*)d_in[9];
  const float* bn1g=(const float*)d_in[10], *bn1b=(const float*)d_in[11];
  const float* bn2g=(const float*)d_in[12], *bn2b=(const float*)d_in[13];
  const float* bn3g=(const float*)d_in[14], *bn3b=(const float*)d_in[15];
  const float* aw1=(const float*)d_in[16], *ab1=(const float*)d_in[17];
  const float* aw2=(const float*)d_in[18], *ab2=(const float*)d_in[19];
  const float* cw1=(const float*)d_in[20], *cb1=(const float*)d_in[21];
  const float* c1g=(const float*)d_in[22], *c1b=(const float*)d_in[23];
  const float* cw2=(const float*)d_in[24], *cb2=(const float*)d_in[25];
  const float* c2g=(const float*)d_in[26], *c2b=(const float*)d_in[27];
  const float* cw3=(const float*)d_in[28], *cb3=(const float*)d_in[29];

  const int N = in_sizes[3];
  const int E = in_sizes[2] / 2;
  const int CNNW = in_sizes[0] / N;   // 768
  const int MOR  = in_sizes[1] / N;   // 6
  const int D = CNNW + MOR;           // 774
  const int Dpad1 = ((D + 63)/64)*64; // 832

  char* p = (char*)d_ws;
  auto alloc = [&](size_t bytes)->char* {
    char* r = p; p += (bytes + 255) & ~(size_t)255; return r;
  };
  unsigned short* hbuf = (unsigned short*)alloc((size_t)N*128*2);  // bf16 h
  float* x1    = (float*)alloc((size_t)N*128*4);
  float* x2    = (float*)alloc((size_t)N*128*4);
  float* dinv  = (float*)alloc((size_t)N*4);
  float* gate  = (float*)alloc((size_t)N*4);
  float* aex   = (float*)alloc((size_t)N*4);
  char* zstart = p;
  int* deg      = (int*)alloc((size_t)N*4);
  unsigned* mg  = (unsigned*)alloc(8*4);
  float* denom  = (float*)alloc(8*4);
  float* pooled = (float*)alloc(8*128*4);
  size_t zbytes = (size_t)(p - zstart);
  int* row_start=(int*)alloc((size_t)(N+1)*4);
  int* cursor  = (int*)alloc((size_t)N*4);
  int* csr_src = (int*)alloc((size_t)E*4);
  int* bsums   = (int*)alloc(4096);
  unsigned short* w1T = (unsigned short*)alloc((size_t)128*Dpad1*2);
  unsigned short* w2T = (unsigned short*)alloc((size_t)128*128*2);
  unsigned short* w3T = (unsigned short*)alloc((size_t)128*128*2);

  hipMemsetAsync(zstart, 0, zbytes, stream);

  const int* srcp = eidx;
  const int* dstp = eidx + E;

  int gE = (E + 255)/256;
  int gN = (N + 255)/256;
  int B  = (N + 1023)/1024;
  int gMfma = (N + 127)/128;
  int gAtt  = (N + 63)/64;
  int gGat  = (N + 15)/16;

  // CSR build
  hist_kernel<<<dim3(gE), dim3(256), 0, stream>>>(dstp, deg, E);
  scan_partial<<<dim3(B), dim3(256), 0, stream>>>(deg, bsums, N);
  scan_bsums<<<dim3(1), dim3(64), 0, stream>>>(bsums, row_start, B, N, E);
  scan_final<<<dim3(B), dim3(256), 0, stream>>>(deg, bsums, row_start, cursor, N);
  dinv_kernel<<<dim3(gN), dim3(256), 0, stream>>>(deg, dinv, N);
  scatter_kernel<<<dim3(gE), dim3(256), 0, stream>>>(srcp, dstp, cursor, csr_src, E);

  // weight pre-convert (bf16, transposed)
  wsplit_kernel<<<dim3((Dpad1+255)/256, 128), dim3(256), 0, stream>>>(g1w, w1T, D, Dpad1);
  wsplit_kernel<<<dim3(1, 128), dim3(256), 0, stream>>>(g2w, w2T, 128, 128);
  wsplit_kernel<<<dim3(1, 128), dim3(256), 0, stream>>>(g3w, w3T, 128, 128);

  // GCN layer 1 (concat input)
  gemm_mfma_kernel<<<dim3(gMfma), dim3(256), 0, stream>>>(cnn, morph, w1T, hbuf, N, CNNW, MOR, Dpad1);
  gather_kernel<<<dim3(gGat), dim3(256), 0, stream>>>(hbuf, dinv, row_start, csr_src,
      g1b, bn1g, bn1b, (const float*)nullptr, (const float*)nullptr, x1, N, 0);
  // GCN layer 2
  gemm_mfma_kernel<<<dim3(gMfma), dim3(256), 0, stream>>>(x1, (const float*)nullptr, w2T, hbuf, N, 128, 0, 128);
  gather_kernel<<<dim3(gGat), dim3(256), 0, stream>>>(hbuf, dinv, row_start, csr_src,
      g2b, bn2g, bn2b, (const float*)nullptr, (const float*)nullptr, x2, N, 0);
  // GCN layer 3 -> x_out = x1+x2+x3 into x1
  gemm_mfma_kernel<<<dim3(gMfma), dim3(256), 0, stream>>>(x2, (const float*)nullptr, w3T, hbuf, N, 128, 0, 128);
  gather_kernel<<<dim3(gGat), dim3(256), 0, stream>>>(hbuf, dinv, row_start, csr_src,
      g3b, bn3g, bn3b, x1, x2, x1, N, 2);

  // attention gate + segment softmax + pooling
  att_kernel<<<dim3(gAtt), dim3(256), 0, stream>>>(x1, aw1, ab1, aw2, ab2, gate, N);
  segmax_kernel<<<dim3(gN), dim3(256), 0, stream>>>(gate, batch, mg, N);
  expsum_kernel<<<dim3(gN), dim3(256), 0, stream>>>(gate, batch, mg, aex, denom, N);
  pooled_kernel<<<dim3(512), dim3(256), 0, stream>>>(aex, x1, batch, pooled, N);

  classifier_kernel<<<dim3(1), dim3(256), 0, stream>>>(pooled, denom,
      cw1, cb1, c1g, c1b, cw2, cb2, c2g, c2b, cw3, cb3, (float*)d_out);
}